// Round 10
// baseline (989.486 us; speedup 1.0000x reference)
//
#include <hip/hip_runtime.h>
#include <cstdint>
#include <cstddef>

// ---------------------------------------------------------------------------
// NeuralODE, multi-kernel, round 10: A-operand direct-from-global (flatmm
// style), LDS carries B only.
//   z' = f(z,t) = tanh([z,t]@W1 + b1) @ W2 + b2, Euler, 20 steps.
//   bs=1024, d=1024, hidden=2048. fp32 in/out; bf16 MFMA inside.
//
// R9 post-mortem: LDS port is the floor (88-96 KB/iter/CU ~ 5 us/kernel),
// and MFMA operand reads dominate it. Fix: A-fragments are 16B-contiguous
// in the K-major activation layout -> load them straight to VGPRs
// (global_load_dwordx4, L1-served across the 2-4 waves sharing them).
// LDS stages B only: 48 KB/iter -> ~2.9 us floor.
// Pipeline: 4 B-buffers (64 KB static), single s_barrier/iter, stage buf
// (i+3)&3 vs compute buf i&3 (no overlap possible), A-regs double-buffered
// one tile ahead. WAITV(6) at loop top retires the 2 oldest B stages;
// compiler's own vmcnt for A-reg uses covers A; no mid-loop vmcnt(0).
// 2D XCD patch swizzle unchanged.
// ---------------------------------------------------------------------------

typedef __bf16 bf16x8 __attribute__((ext_vector_type(8)));
typedef float f32x4 __attribute__((ext_vector_type(4)));

#define WAITV(N) asm volatile("s_waitcnt vmcnt(" #N ") lgkmcnt(0)" ::: "memory")
#define BARRIER() asm volatile("s_barrier" ::: "memory")

__device__ __forceinline__ unsigned short f2bf(float f) {
  union { float f; unsigned u; } v; v.f = f;
  unsigned r = v.u + 0x7fffu + ((v.u >> 16) & 1u);   // RNE
  return (unsigned short)(r >> 16);
}

// fast tanh: 1 - 2/(1+2^(2*log2e*x)); exact at +/-inf
__device__ __forceinline__ float fast_tanh(float x) {
  float e = __builtin_amdgcn_exp2f(x * 2.8853900817779268f);
  return 1.0f - 2.0f * __builtin_amdgcn_rcpf(1.0f + e);
}

// ---------------- prep: tiled transpose fp32 -> bf16 (out[cols][rows]) ------
__global__ void transpose_to_bf16(const float* __restrict__ in,
                                  unsigned short* __restrict__ out,
                                  int rows, int cols) {
  __shared__ float tile[32][33];
  int c0 = blockIdx.x * 32, r0 = blockIdx.y * 32;
  int tx = threadIdx.x, ty = threadIdx.y;
#pragma unroll
  for (int j = 0; j < 32; j += 8)
    tile[ty + j][tx] = in[(size_t)(r0 + ty + j) * cols + (c0 + tx)];
  __syncthreads();
#pragma unroll
  for (int j = 0; j < 32; j += 8)
    out[(size_t)(c0 + ty + j) * rows + (r0 + tx)] = f2bf(tile[tx][ty + j]);
}

// ---------------- prep: z copies + last W1 row ------------------------------
__global__ void prep_misc(const float* __restrict__ z0,
                          float* __restrict__ zf,
                          unsigned short* __restrict__ zbf,
                          const float* __restrict__ W1,
                          float* __restrict__ w1l, int n, int nl) {
  int i = blockIdx.x * blockDim.x + threadIdx.x;
  if (i < n) { float v = z0[i]; zf[i] = v; zbf[i] = f2bf(v); }
  if (i < nl) { w1l[i] = W1[(size_t)1024 * 2048 + i]; }
}

// stage 64 rows x 64 bf16 (8 KB) with 512 threads via global_load_lds,
// XOR-swizzled 16B chunks: row r slot s holds logical chunk s^(r&7).
__device__ __forceinline__ void stage64(const unsigned short* __restrict__ g,
                                        size_t ld, int row0, int k0,
                                        unsigned short* lds, int tid) {
  int r = tid >> 3;
  int c = (tid & 7) ^ (r & 7);
  __builtin_amdgcn_global_load_lds(
      (const __attribute__((address_space(1))) void*)(
          g + (size_t)(row0 + r) * ld + k0 + c * 8),
      (__attribute__((address_space(3))) void*)(lds + tid * 8), 16, 0, 0);
}

__device__ __forceinline__ bf16x8 frag_ld(const unsigned short* lds, int row,
                                          int chunk_logical, int x) {
  return *(const bf16x8*)(lds + row * 64 + ((chunk_logical ^ x) << 3));
}

// ---------------- GEMM1: H = tanh(Zb @ W1T^T + b1 + t*w1l) ------------------
// 64x128 block, K=1024 (16 BK=64 tiles), 512 thr = 8 waves (2m x 4n, 32x32).
// LDS: 4 bufs x 8192 shorts (B: 128 W1T rows x 64 k). A direct from global.
__global__ __launch_bounds__(512, 1) void gemm1_kernel(
    const unsigned short* __restrict__ Zb,    // [1024][1024] bf16
    const unsigned short* __restrict__ W1T,   // [2048][1024] bf16 (N-major)
    unsigned short* __restrict__ H,           // [1024][2048] bf16
    const float* __restrict__ b1, const float* __restrict__ w1l, float tval) {
  __shared__ __align__(16) unsigned short lds[32768];  // 64 KB = 4 x 16 KB
  const int tid = threadIdx.x;
  const int lane = tid & 63, wid = tid >> 6;
  const int l15 = lane & 15, q = lane >> 4, x = l15 & 7;
  const int bid = blockIdx.x;
  const int xcd = bid & 7, loc = bid >> 3;
  const int mt = (loc & 3) | ((xcd & 3) << 2);    // 16 m-tiles, 4/XCD
  const int nt = (loc >> 2) | ((xcd >> 2) << 3);  // 16 n-tiles, 8/XCD
  const int m0 = mt * 64, n0 = nt * 128;
  const int wm = (wid & 1) * 32, wn = (wid >> 1) * 32;

  // per-lane A base: row m0+wm+l15 (im adds 16 rows), k offset q*8 (+kk*32)
  const unsigned short* gA = Zb + (size_t)(m0 + wm + l15) * 1024 + q * 8;

  f32x4 acc[2][2] = {};
  bf16x8 a0r[2][2], a1r[2][2];

  auto stageB = [&](int t, int b) {   // 2 loads/thread
    int k = t * 64;
    unsigned short* p = lds + b * 8192;
    stage64(W1T, 1024, n0, k, p, tid);
    stage64(W1T, 1024, n0 + 64, k, p + 4096, tid);
  };
  auto loadA = [&](int t, bf16x8 dst[2][2]) {   // 4 loads/thread
    int k = t * 64;
#pragma unroll
    for (int kk = 0; kk < 2; ++kk)
#pragma unroll
      for (int im = 0; im < 2; ++im)
        dst[kk][im] =
            *(const bf16x8*)(gA + (size_t)(im * 16) * 1024 + k + kk * 32);
  };
  auto compute = [&](int b, bf16x8 (&ar)[2][2]) {
    const unsigned short* B = lds + b * 8192;
#pragma unroll
    for (int kk = 0; kk < 2; ++kk) {
      bf16x8 bb[2];
#pragma unroll
      for (int jn = 0; jn < 2; ++jn)
        bb[jn] = frag_ld(B, wn + jn * 16 + l15, (kk << 2) + q, x);
#pragma unroll
      for (int im = 0; im < 2; ++im)
#pragma unroll
        for (int jn = 0; jn < 2; ++jn)
          acc[im][jn] = __builtin_amdgcn_mfma_f32_16x16x32_bf16(
              ar[kk][im], bb[jn], acc[im][jn], 0, 0, 0);
    }
  };

  // prologue: B first, then A (keeps WAITV(6) able to retire B0 first)
  stageB(0, 0);
  stageB(1, 1);
  stageB(2, 2);
  loadA(0, a0r);
#pragma unroll 1
  for (int i = 0; i < 16; i += 2) {
    WAITV(6);
    BARRIER();
    if (i < 15) loadA(i + 1, a1r);
    __builtin_amdgcn_sched_barrier(0);
    if (i < 13) stageB(i + 3, (i + 3) & 3);
    compute(i & 3, a0r);

    WAITV(6);
    BARRIER();
    if (i + 1 < 15) loadA(i + 2, a0r);
    __builtin_amdgcn_sched_barrier(0);
    if (i + 1 < 13) stageB(i + 4, (i + 4) & 3);
    compute((i + 1) & 3, a1r);
  }

#pragma unroll
  for (int jn = 0; jn < 2; ++jn) {
    int col = n0 + wn + jn * 16 + l15;
    float bb = b1[col] + tval * w1l[col];
#pragma unroll
    for (int im = 0; im < 2; ++im) {
      int rowb = m0 + wm + im * 16 + q * 4;
#pragma unroll
      for (int r = 0; r < 4; ++r)
        H[(size_t)(rowb + r) * 2048 + col] =
            f2bf(fast_tanh(acc[im][jn][r] + bb));
    }
  }
}

// ---------------- GEMM2: z' = zf + h*(H @ W2T^T + b2) -----------------------
// 64x64 block, K=2048 split as kh halves (16 tiles of 64 per half), 512 thr =
// 8 waves (kh = wid>>2, mh, nh; 32x32 each). LDS: 4 bufs x 8192 shorts (B:
// 64 W2T rows x 64 k x 2 kh-halves). A (H) direct from global. f32 reduce.
__global__ __launch_bounds__(512, 1) void gemm2_kernel(
    const unsigned short* __restrict__ Hb,    // [1024][2048] bf16
    const unsigned short* __restrict__ W2T,   // [1024][2048] bf16 (N-major)
    const float* __restrict__ b2,
    const float* __restrict__ zf,
    float* __restrict__ outf,                 // zf, or d_out on last step
    unsigned short* __restrict__ zbf,
    float h) {
  __shared__ __align__(16) unsigned short lds[32768];  // 64 KB = 4 x 16 KB
  const int tid = threadIdx.x;
  const int lane = tid & 63, wid = tid >> 6;
  const int l15 = lane & 15, q = lane >> 4, x = l15 & 7;
  const int kh = wid >> 2, mh = (wid >> 1) & 1, nh = wid & 1;
  const int bid = blockIdx.x;
  const int xcd = bid & 7, loc = bid >> 3;
  const int mt = (loc & 3) | ((xcd & 3) << 2);    // 16 m-tiles, 4/XCD
  const int nt = (loc >> 2) | ((xcd >> 2) << 3);  // 16 n-tiles, 8/XCD
  const int m0 = mt * 64, n0 = nt * 64;

  // per-lane A base: row m0+mh*32+l15, K-half kh, k offset q*8 (+kk*32)
  const unsigned short* gA =
      Hb + (size_t)(m0 + mh * 32 + l15) * 2048 + kh * 1024 + q * 8;

  f32x4 acc[2][2] = {};
  bf16x8 a0r[2][2], a1r[2][2];

  auto stageB = [&](int t, int b) {   // 2 loads/thread
    int k = t * 64;
    unsigned short* p = lds + b * 8192;
    stage64(W2T, 2048, n0, k, p, tid);                // kh=0 half
    stage64(W2T, 2048, n0, k + 1024, p + 4096, tid);  // kh=1 half
  };
  auto loadA = [&](int t, bf16x8 dst[2][2]) {   // 4 loads/thread
    int k = t * 64;
#pragma unroll
    for (int kk = 0; kk < 2; ++kk)
#pragma unroll
      for (int im = 0; im < 2; ++im)
        dst[kk][im] =
            *(const bf16x8*)(gA + (size_t)(im * 16) * 2048 + k + kk * 32);
  };
  auto compute = [&](int b, bf16x8 (&ar)[2][2]) {
    const unsigned short* B = lds + b * 8192 + kh * 4096;
#pragma unroll
    for (int kk = 0; kk < 2; ++kk) {
      bf16x8 bb[2];
#pragma unroll
      for (int jn = 0; jn < 2; ++jn)
        bb[jn] = frag_ld(B, nh * 32 + jn * 16 + l15, (kk << 2) + q, x);
#pragma unroll
      for (int im = 0; im < 2; ++im)
#pragma unroll
        for (int jn = 0; jn < 2; ++jn)
          acc[im][jn] = __builtin_amdgcn_mfma_f32_16x16x32_bf16(
              ar[kk][im], bb[jn], acc[im][jn], 0, 0, 0);
    }
  };

  stageB(0, 0);
  stageB(1, 1);
  stageB(2, 2);
  loadA(0, a0r);
#pragma unroll 1
  for (int i = 0; i < 16; i += 2) {
    WAITV(6);
    BARRIER();
    if (i < 15) loadA(i + 1, a1r);
    __builtin_amdgcn_sched_barrier(0);
    if (i < 13) stageB(i + 3, (i + 3) & 3);
    compute(i & 3, a0r);

    WAITV(6);
    BARRIER();
    if (i + 1 < 15) loadA(i + 2, a0r);
    __builtin_amdgcn_sched_barrier(0);
    if (i + 1 < 13) stageB(i + 4, (i + 4) & 3);
    compute((i + 1) & 3, a1r);
  }

  // K-split reduce: kh=1 waves publish to LDS (f32, stride 33), kh=0 add.
  __syncthreads();
  float* red = (float*)lds;
  const int region = (mh * 2 + nh) * 1056;   // 32*33 floats per (mh,nh)
  if (kh == 1) {
#pragma unroll
    for (int im = 0; im < 2; ++im)
#pragma unroll
      for (int jn = 0; jn < 2; ++jn) {
        int c = jn * 16 + l15;
#pragma unroll
        for (int r = 0; r < 4; ++r)
          red[region + (im * 16 + q * 4 + r) * 33 + c] = acc[im][jn][r];
      }
  }
  __syncthreads();
  if (kh == 0) {
#pragma unroll
    for (int jn = 0; jn < 2; ++jn) {
      int coll = nh * 32 + jn * 16 + l15;
      int col = n0 + coll;
      float bb = b2[col];
#pragma unroll
      for (int im = 0; im < 2; ++im) {
        int rowl = im * 16 + q * 4;
#pragma unroll
        for (int r = 0; r < 4; ++r) {
          float s = acc[im][jn][r] +
                    red[region + (rowl + r) * 33 + jn * 16 + l15];
          size_t gidx = (size_t)(m0 + mh * 32 + rowl + r) * 1024 + col;
          float zv = zf[gidx] + h * (s + bb);
          outf[gidx] = zv;
          zbf[gidx] = f2bf(zv);
        }
      }
    }
  }
}

// ---------------------------------------------------------------------------
extern "C" void kernel_launch(void* const* d_in, const int* in_sizes, int n_in,
                              void* d_out, int out_size, void* d_ws,
                              size_t ws_size, hipStream_t stream) {
  const float* z0 = (const float*)d_in[0];
  // d_in[1] = t (linspace 0..1, 5) — reproduced exactly in f32 arithmetic
  const float* W1 = (const float*)d_in[2];
  const float* b1 = (const float*)d_in[3];
  const float* W2 = (const float*)d_in[4];
  const float* b2 = (const float*)d_in[5];
  float* out = (float*)d_out;

  char* ws = (char*)d_ws;
  unsigned short* W1T = (unsigned short*)(ws + 0);              // 4 MB
  unsigned short* W2T = (unsigned short*)(ws + (4u << 20));     // 4 MB
  unsigned short* zbf = (unsigned short*)(ws + (8u << 20));     // 2 MB
  unsigned short* Hbf = (unsigned short*)(ws + (10u << 20));    // 4 MB
  float* zf = (float*)(ws + (14u << 20));                       // 4 MB
  float* w1l = (float*)(ws + (18u << 20));                      // 8 KB

  transpose_to_bf16<<<dim3(64, 32), dim3(32, 8), 0, stream>>>(W1, W1T, 1024, 2048);
  transpose_to_bf16<<<dim3(32, 64), dim3(32, 8), 0, stream>>>(W2, W2T, 2048, 1024);
  prep_misc<<<4096, 256, 0, stream>>>(z0, zf, zbf, W1, w1l, 1024 * 1024, 2048);

  const float h = 0.05f;  // (t[i+1]-t[i])/5 in f32 == 0.05f for all segments
  for (int seg = 0; seg < 4; ++seg) {
    float tcur = 0.25f * (float)seg;  // t[seg] (exact in f32)
    for (int j = 0; j < 5; ++j) {
      gemm1_kernel<<<256, 512, 0, stream>>>(zbf, W1T, Hbf, b1, w1l, tcur);
      bool last = (seg == 3 && j == 4);
      float* outf = last ? out : zf;
      gemm2_kernel<<<256, 512, 0, stream>>>(Hbf, W2T, b2, zf, outf, zbf, h);
      tcur += h;  // matches reference's sequential f32 accumulation
    }
  }
}

// Round 11
// 928.947 us; speedup vs baseline: 1.0652x; 1.0652x over previous
//
#include <hip/hip_runtime.h>
#include <cstdint>
#include <cstddef>

// ---------------------------------------------------------------------------
// NeuralODE, multi-kernel, round 11: 64x64 wave tiles (mfma_32x32x16).
//   z' = f(z,t) = tanh([z,t]@W1 + b1) @ W2 + b2, Euler, 20 steps.
//   bs=1024, d=1024, hidden=2048. fp32 in/out; bf16 MFMA inside.
//
// R10 lesson: A-direct-from-global is TA-bound (16 cache lines per frag
// load) -> revert to LDS staging. R9 corrected model: LDS-port bound;
// read bytes/MAC = 2(Mw+Nw)/(Mw*Nw) -> 64x64 wave tiles halve it.
//   gemm1: grid 256, block 64x128, 128 thr = 2 waves of 64x64, K=1024.
//   gemm2: grid 256, block 64x64, 2 waves K-split (1024 each) + f32 reduce.
// mfma_f32_32x32x16_bf16: A[m=lane&31][k=(lane>>5)*8+j]; C col=lane&31,
// row=(reg&3)+8*(reg>>2)+4*(lane>>5)  [m74/m101 verified].
// Swizzle key extended to (r^(r>>3))&7 for 32-row fragment phases.
// Pipeline = R9-proven: WAITV(L); barrier; compute; barrier; stage.
// ---------------------------------------------------------------------------

typedef __bf16 bf16x8 __attribute__((ext_vector_type(8)));
typedef float f32x16 __attribute__((ext_vector_type(16)));

#define WAITV(N) asm volatile("s_waitcnt vmcnt(" #N ") lgkmcnt(0)" ::: "memory")
#define BARRIER() asm volatile("s_barrier" ::: "memory")

__device__ __forceinline__ unsigned short f2bf(float f) {
  union { float f; unsigned u; } v; v.f = f;
  unsigned r = v.u + 0x7fffu + ((v.u >> 16) & 1u);   // RNE
  return (unsigned short)(r >> 16);
}

__device__ __forceinline__ float fast_tanh(float x) {
  float e = __builtin_amdgcn_exp2f(x * 2.8853900817779268f);
  return 1.0f - 2.0f * __builtin_amdgcn_rcpf(1.0f + e);
}

// ---------------- prep: tiled transpose fp32 -> bf16 (out[cols][rows]) ------
__global__ void transpose_to_bf16(const float* __restrict__ in,
                                  unsigned short* __restrict__ out,
                                  int rows, int cols) {
  __shared__ float tile[32][33];
  int c0 = blockIdx.x * 32, r0 = blockIdx.y * 32;
  int tx = threadIdx.x, ty = threadIdx.y;
#pragma unroll
  for (int j = 0; j < 32; j += 8)
    tile[ty + j][tx] = in[(size_t)(r0 + ty + j) * cols + (c0 + tx)];
  __syncthreads();
#pragma unroll
  for (int j = 0; j < 32; j += 8)
    out[(size_t)(c0 + ty + j) * rows + (r0 + tx)] = f2bf(tile[tx][ty + j]);
}

// ---------------- prep: z copies + last W1 row ------------------------------
__global__ void prep_misc(const float* __restrict__ z0,
                          float* __restrict__ zf,
                          unsigned short* __restrict__ zbf,
                          const float* __restrict__ W1,
                          float* __restrict__ w1l, int n, int nl) {
  int i = blockIdx.x * blockDim.x + threadIdx.x;
  if (i < n) { float v = z0[i]; zf[i] = v; zbf[i] = f2bf(v); }
  if (i < nl) { w1l[i] = W1[(size_t)1024 * 2048 + i]; }
}

// swizzle key for row r (region-local): spreads 32-row fragment phases.
__device__ __forceinline__ int swz(int r) { return (r ^ (r >> 3)) & 7; }

// stage 16 rows x 64 bf16 (2 KB) with 128 threads via global_load_lds.
// Region layout: row-major 64 shorts/row; 16B chunk c stored at slot c^swz(rl).
__device__ __forceinline__ void stage16(const unsigned short* __restrict__ g,
                                        size_t ld, int grow0, int k0,
                                        unsigned short* region, int lrow0,
                                        int tid) {
  int rr = tid >> 3;                 // 0..15
  int rl = lrow0 + rr;               // region-local row
  int c = (tid & 7) ^ swz(rl);       // logical chunk to fetch
  __builtin_amdgcn_global_load_lds(
      (const __attribute__((address_space(1))) void*)(
          g + (size_t)(grow0 + rr) * ld + k0 + c * 8),
      (__attribute__((address_space(3))) void*)(region + lrow0 * 64 + tid * 8),
      16, 0, 0);
}

// read logical chunk c (0..7) of region row
__device__ __forceinline__ bf16x8 frag64(const unsigned short* region, int row,
                                         int c) {
  return *(const bf16x8*)(region + row * 64 + ((c ^ swz(row)) << 3));
}

// ---------------- GEMM1: H = tanh(Zb @ W1T^T + b1 + t*w1l) ------------------
// block 64x128, 128 thr = 2 waves (n-halves) of 64x64, K=1024 (16 BK=64).
// LDS: 2 bufs x (A 64x64 + B 128x64) = 2 x 24 KB = 48 KB.
__global__ __launch_bounds__(128) void gemm1_kernel(
    const unsigned short* __restrict__ Zb,    // [1024][1024] bf16
    const unsigned short* __restrict__ W1T,   // [2048][1024] bf16 (N-major)
    unsigned short* __restrict__ H,           // [1024][2048] bf16
    const float* __restrict__ b1, const float* __restrict__ w1l, float tval) {
  __shared__ __align__(16) unsigned short lds[24576];  // 48 KB
  const int tid = threadIdx.x;
  const int lane = tid & 63, wid = tid >> 6;  // 2 waves
  const int l31 = lane & 31, h5 = lane >> 5;  // frag row / k-group
  const int bid = blockIdx.x;
  const int xcd = bid & 7, loc = bid >> 3;
  const int mt = (loc & 3) | ((xcd & 3) << 2);    // 16 m-tiles, 4/XCD
  const int nt = (loc >> 2) | ((xcd >> 2) << 3);  // 16 n-tiles, 8/XCD
  const int m0 = mt * 64, n0 = nt * 128;

  f32x16 acc[2][2] = {};   // [im][jn], wave tile 64x64

  auto stage_tile = [&](int t, int b) {   // 12 loads/thread
    int k = t * 64;
    unsigned short* A = lds + b * 12288;
    unsigned short* B = lds + b * 12288 + 4096;
#pragma unroll
    for (int s = 0; s < 4; ++s)
      stage16(Zb, 1024, m0 + s * 16, k, A, s * 16, tid);
#pragma unroll
    for (int s = 0; s < 8; ++s)
      stage16(W1T, 1024, n0 + s * 16, k, B, s * 16, tid);
  };
  auto compute = [&](int b) {
    const unsigned short* A = lds + b * 12288;
    const unsigned short* B = lds + b * 12288 + 4096;
#pragma unroll
    for (int ks = 0; ks < 4; ++ks) {       // K=16 per MFMA
      int c = ks * 2 + h5;                 // 16B chunk index
      bf16x8 a[2], bb[2];
#pragma unroll
      for (int im = 0; im < 2; ++im) a[im] = frag64(A, im * 32 + l31, c);
#pragma unroll
      for (int jn = 0; jn < 2; ++jn)
        bb[jn] = frag64(B, wid * 64 + jn * 32 + l31, c);
#pragma unroll
      for (int im = 0; im < 2; ++im)
#pragma unroll
        for (int jn = 0; jn < 2; ++jn)
          acc[im][jn] = __builtin_amdgcn_mfma_f32_32x32x16_bf16(
              a[im], bb[jn], acc[im][jn], 0, 0, 0);
    }
  };

  stage_tile(0, 0);
  stage_tile(1, 1);
#pragma unroll 1
  for (int i = 0; i < 15; ++i) {
    WAITV(12);                    // tile i done; tile i+1 (12 loads) in flight
    BARRIER();
    compute(i & 1);
    if (i < 14) {
      BARRIER();                  // all waves done reading buf i&1
      stage_tile(i + 2, i & 1);
    }
  }
  WAITV(0);
  BARRIER();
  compute(1);   // tile 15

  // epilogue: C row = (j&3) + 8*(j>>2) + 4*h5 (+im*32); col = l31 (+jn*32)
#pragma unroll
  for (int jn = 0; jn < 2; ++jn) {
    int col = n0 + wid * 64 + jn * 32 + l31;
    float bb = b1[col] + tval * w1l[col];
#pragma unroll
    for (int im = 0; im < 2; ++im) {
      int rowb = m0 + im * 32 + 4 * h5;
#pragma unroll
      for (int j = 0; j < 16; ++j) {
        int row = rowb + (j & 3) + 8 * (j >> 2);
        H[(size_t)row * 2048 + col] = f2bf(fast_tanh(acc[im][jn][j] + bb));
      }
    }
  }
}

// ---------------- GEMM2: z' = zf + h*(H @ W2T^T + b2) -----------------------
// block 64x64, 128 thr = 2 waves, K-split: wave kh covers K in
// [kh*1024, +1024), each a full 64x64 tile; f32 LDS reduce (stride 65).
// LDS: 2 bufs x (A0,A1,B0,B1 of 4 KB) = 2 x 32 KB = 64 KB.
__global__ __launch_bounds__(128) void gemm2_kernel(
    const unsigned short* __restrict__ Hb,    // [1024][2048] bf16
    const unsigned short* __restrict__ W2T,   // [1024][2048] bf16 (N-major)
    const float* __restrict__ b2,
    const float* __restrict__ zf,
    float* __restrict__ outf,                 // zf, or d_out on last step
    unsigned short* __restrict__ zbf,
    float h) {
  __shared__ __align__(16) unsigned short lds[32768];  // 64 KB
  const int tid = threadIdx.x;
  const int lane = tid & 63, kh = tid >> 6;   // wave = K-half
  const int l31 = lane & 31, h5 = lane >> 5;
  const int bid = blockIdx.x;
  const int xcd = bid & 7, loc = bid >> 3;
  const int mt = (loc & 3) | ((xcd & 3) << 2);    // 16 m-tiles, 4/XCD
  const int nt = (loc >> 2) | ((xcd >> 2) << 3);  // 16 n-tiles, 8/XCD
  const int m0 = mt * 64, n0 = nt * 64;

  f32x16 acc[2][2] = {};   // [im][jn], 64x64 per wave

  auto stage_tile = [&](int t, int b) {   // 16 loads/thread
    int k = t * 64;
    unsigned short* p = lds + b * 16384;
#pragma unroll
    for (int kk = 0; kk < 2; ++kk) {
      unsigned short* A = p + kk * 4096;
      unsigned short* B = p + 8192 + kk * 4096;
#pragma unroll
      for (int s = 0; s < 4; ++s)
        stage16(Hb, 2048, m0 + s * 16, k + kk * 1024, A, s * 16, tid);
#pragma unroll
      for (int s = 0; s < 4; ++s)
        stage16(W2T, 2048, n0 + s * 16, k + kk * 1024, B, s * 16, tid);
    }
  };
  auto compute = [&](int b) {
    const unsigned short* A = lds + b * 16384 + kh * 4096;
    const unsigned short* B = lds + b * 16384 + 8192 + kh * 4096;
#pragma unroll
    for (int ks = 0; ks < 4; ++ks) {
      int c = ks * 2 + h5;
      bf16x8 a[2], bb[2];
#pragma unroll
      for (int im = 0; im < 2; ++im) a[im] = frag64(A, im * 32 + l31, c);
#pragma unroll
      for (int jn = 0; jn < 2; ++jn) bb[jn] = frag64(B, jn * 32 + l31, c);
#pragma unroll
      for (int im = 0; im < 2; ++im)
#pragma unroll
        for (int jn = 0; jn < 2; ++jn)
          acc[im][jn] = __builtin_amdgcn_mfma_f32_32x32x16_bf16(
              a[im], bb[jn], acc[im][jn], 0, 0, 0);
    }
  };

  stage_tile(0, 0);
  stage_tile(1, 1);
#pragma unroll 1
  for (int i = 0; i < 15; ++i) {
    WAITV(16);                    // tile i done; tile i+1 (16 loads) in flight
    BARRIER();
    compute(i & 1);
    if (i < 14) {
      BARRIER();
      stage_tile(i + 2, i & 1);
    }
  }
  WAITV(0);
  BARRIER();
  compute(1);   // tile 15

  // reduce: kh=1 publishes 64x64 f32 (stride 65) into buf0; kh=0 adds.
  __syncthreads();
  float* red = (float*)lds;
  if (kh == 1) {
#pragma unroll
    for (int im = 0; im < 2; ++im) {
      int rowb = im * 32 + 4 * h5;
#pragma unroll
      for (int jn = 0; jn < 2; ++jn) {
        int col = jn * 32 + l31;
#pragma unroll
        for (int j = 0; j < 16; ++j)
          red[(rowb + (j & 3) + 8 * (j >> 2)) * 65 + col] = acc[im][jn][j];
      }
    }
  }
  __syncthreads();
  if (kh == 0) {
#pragma unroll
    for (int jn = 0; jn < 2; ++jn) {
      int col = n0 + jn * 32 + l31;
      float bb = b2[col];
#pragma unroll
      for (int im = 0; im < 2; ++im) {
        int rowb = im * 32 + 4 * h5;
#pragma unroll
        for (int j = 0; j < 16; ++j) {
          int rl = rowb + (j & 3) + 8 * (j >> 2);
          float s = acc[im][jn][j] + red[rl * 65 + jn * 32 + l31];
          size_t gidx = (size_t)(m0 + rl) * 1024 + col;
          float zv = zf[gidx] + h * (s + bb);
          outf[gidx] = zv;
          zbf[gidx] = f2bf(zv);
        }
      }
    }
  }
}

// ---------------------------------------------------------------------------
extern "C" void kernel_launch(void* const* d_in, const int* in_sizes, int n_in,
                              void* d_out, int out_size, void* d_ws,
                              size_t ws_size, hipStream_t stream) {
  const float* z0 = (const float*)d_in[0];
  // d_in[1] = t (linspace 0..1, 5) — reproduced exactly in f32 arithmetic
  const float* W1 = (const float*)d_in[2];
  const float* b1 = (const float*)d_in[3];
  const float* W2 = (const float*)d_in[4];
  const float* b2 = (const float*)d_in[5];
  float* out = (float*)d_out;

  char* ws = (char*)d_ws;
  unsigned short* W1T = (unsigned short*)(ws + 0);              // 4 MB
  unsigned short* W2T = (unsigned short*)(ws + (4u << 20));     // 4 MB
  unsigned short* zbf = (unsigned short*)(ws + (8u << 20));     // 2 MB
  unsigned short* Hbf = (unsigned short*)(ws + (10u << 20));    // 4 MB
  float* zf = (float*)(ws + (14u << 20));                       // 4 MB
  float* w1l = (float*)(ws + (18u << 20));                      // 8 KB

  transpose_to_bf16<<<dim3(64, 32), dim3(32, 8), 0, stream>>>(W1, W1T, 1024, 2048);
  transpose_to_bf16<<<dim3(32, 64), dim3(32, 8), 0, stream>>>(W2, W2T, 2048, 1024);
  prep_misc<<<4096, 256, 0, stream>>>(z0, zf, zbf, W1, w1l, 1024 * 1024, 2048);

  const float h = 0.05f;  // (t[i+1]-t[i])/5 in f32 == 0.05f for all segments
  for (int seg = 0; seg < 4; ++seg) {
    float tcur = 0.25f * (float)seg;  // t[seg] (exact in f32)
    for (int j = 0; j < 5; ++j) {
      gemm1_kernel<<<256, 128, 0, stream>>>(zbf, W1T, Hbf, b1, w1l, tcur);
      bool last = (seg == 3 && j == 4);
      float* outf = last ? out : zf;
      gemm2_kernel<<<256, 128, 0, stream>>>(Hbf, W2T, b2, zf, outf, zbf, h);
      tcur += h;  // matches reference's sequential f32 accumulation
    }
  }
}